// Round 4
// baseline (125.398 us; speedup 1.0000x reference)
//
#include <hip/hip_runtime.h>
#include <math.h>

// Problem constants (from reference / setup_inputs)
#define N_ROIS   32
#define N_CAT    (N_ROIS * 9)      // 288 cat_rois rows
#define C_FEAT   256
#define H_FEAT   40
#define W_FEAT   40
#define P_FEAT   (H_FEAT * W_FEAT) // 1600 pixels
#define PH       7
#define PW       7
#define SCALE    0.0625f
#define MIN_SIZE 16.0f
#define CELLS    (PH * PW)                 // 49
#define POOL_PER_BOX (C_FEAT * CELLS)      // 12544
#define OUT_POOL_ELEMS ((size_t)N_CAT * POOL_PER_BOX)  // 3,612,672

#define POOL_BLKS (PH * N_CAT)             // 2016 blocks = (pooled row, box)
#define TPB       128                      // 2 waves; thread owns ch c, c+128

// ---------------------------------------------------------------------------
// v4: ONE lean fused kernel. No workspace, no transpose, no LDS staging,
// no predicates, no second launch.
//
// Evidence driving this design:
//  * R1 (fused, 1 launch): graded 100.7 with kernel measured 43.6us ->
//    single-launch fixed overhead = 57.1us (unconditional 256MiB poison
//    fill ~41.5 + out poison + graph/launch overhead). Two-launch rounds
//    all sit 82-86 with kernels <41 -> the 2nd launch + dependency costs
//    ~15-25us. So: exactly one launch, and make the kernel lean.
//  * R2 counters (VALUBusy 38.5% at 25% occupancy, bank-conflicts ~0)
//    showed R1's 43.6us was ~2500 VALU inst/thread of predicate emulation
//    (v_cmp x2+and+fmax+cndmask per element) and div/mod staging of
//    BLOCK-UNIFORM bounds. v3's fix: readfirstlane bounds to SGPRs and
//    use plain dynamic loops -> inner body = load + v_max_f32 only.
//
// Geometry (context anchor + IoU over 32 rois) is recomputed redundantly
// per block, wave-uniform (~650 inst; 4032 waves -> ~2us aggregate).
// Pool reads NCHW f directly (1.6MB, fully L2-resident): per thread
// 2 channels x ~2.5 rows x ~12 cols of scalar loads, ~250MB L2 traffic
// ~8us at 16 waves/CU.
// ---------------------------------------------------------------------------
__global__ __launch_bounds__(TPB) void
fused_v4(const float* __restrict__ f,
         const float* __restrict__ rois,
         const int* __restrict__ hh_p,
         const int* __restrict__ hw_p,
         float* __restrict__ out) {
    __shared__ float R[N_ROIS * 5];

    const int i   = blockIdx.x / N_CAT;   // pooled row 0..6
    const int b   = blockIdx.x % N_CAT;   // box 0..287 (fast -> XCD = b%8)
    const int tid = threadIdx.x;

    for (int t = tid; t < N_ROIS * 5; t += TPB) R[t] = rois[t];
    __syncthreads();

    // ---- box geometry (block-uniform; all lanes redundantly) ----
    const int n  = b / 9;
    const int jj = b % 9;
    const float x1 = R[n * 5 + 1], y1 = R[n * 5 + 2];
    const float x2 = R[n * 5 + 3], y2 = R[n * 5 + 4];
    float bx1, by1, bx2, by2;

    if (jj == 0) {                 // parent roi row
        bx1 = x1; by1 = y1; bx2 = x2; by2 = y2;
    } else {
        const int j = jj - 1;
        const int m = (j < 4) ? j : j + 1;   // skip center of 3x3
        const int r  = m / 3;
        const int cc = m % 3;
        const float w = x2 - x1, h = y2 - y1;
        const float cx = x1 + w * ((float)cc - 0.5f);
        const float cy = y1 + h * ((float)r  - 0.5f);
        bx1 = cx - w * 0.25f;
        by1 = cy - h * 0.25f;
        bx2 = cx + w * 0.25f;
        by2 = cy + h * 0.25f;
        const float bw = bx2 - bx1 + 1.0f;
        const float bh = by2 - by1 + 1.0f;
        const float hh = (float)(*hh_p);
        const float hw = (float)(*hw_p);
        const bool invalid = (bx1 < 0.0f) || (by1 < 0.0f) ||
                             (bx2 >= hw) || (by2 >= hh) ||
                             (bw < MIN_SIZE) || (bh < MIN_SIZE);
        if (invalid) { bx1 = x1; by1 = y1; bx2 = x2; by2 = y2; }

        const float gw = bx2 - bx1 + 1.0f;
        const float gh = by2 - by1 + 1.0f;
        const float garea = gw * gh;
        const bool gdeg = (gw == 1.0f) && (gh == 1.0f);

        float best_ov = -INFINITY;
        int best = 0;
        for (int a = 0; a < N_ROIS; ++a) {
            const float ax1 = R[a * 5 + 1], ay1 = R[a * 5 + 2];
            const float ax2 = R[a * 5 + 3], ay2 = R[a * 5 + 4];
            const float aw = ax2 - ax1 + 1.0f, ah = ay2 - ay1 + 1.0f;
            float iw = fminf(ax2, bx2) - fmaxf(ax1, bx1) + 1.0f;
            float ih = fminf(ay2, by2) - fmaxf(ay1, by1) + 1.0f;
            iw = fmaxf(iw, 0.0f);
            ih = fmaxf(ih, 0.0f);
            const float inter = iw * ih;
            float ov = inter / (aw * ah + garea - inter);
            if (gdeg) ov = 0.0f;
            if (aw == 1.0f && ah == 1.0f) ov = -1.0f;
            if (ov > best_ov) { best_ov = ov; best = a; }  // first-max tie
        }

        bool label = (best_ov >= 0.3f);
        const float w_cell = bx2 - bx1;
        const float h_cell = by2 - by1;
        const float rw = label ? (R[best * 5 + 3] - R[best * 5 + 1]) : 0.0f;
        const float rh = label ? (R[best * 5 + 4] - R[best * 5 + 2]) : 0.0f;
        label = label &&
                !(fmaxf(rw, rh) >= fmaxf(w_cell, h_cell)) &&
                !(fminf(rw, rh) < fminf(w_cell, h_cell) / 3.0f);
        if (label) {
            bx1 = R[best * 5 + 1]; by1 = R[best * 5 + 2];
            bx2 = R[best * 5 + 3]; by2 = R[best * 5 + 4];
        }
    }

    // cat_rois output row (one writer per box)
    if (i == 0 && tid == 0) {
        float* row = out + OUT_POOL_ELEMS + (size_t)b * 5;
        if (jj == 0) {
            #pragma unroll
            for (int t = 0; t < 5; ++t) row[t] = R[n * 5 + t];
        } else {
            row[0] = 0.0f;
            row[1] = bx1; row[2] = by1; row[3] = bx2; row[4] = by2;
        }
    }

    // ---- pooling geometry (block-uniform -> SGPRs) ----
    // jnp.round = round-half-to-even = rintf (default rounding mode)
    const float sw = rintf(bx1 * SCALE);
    const float sh = rintf(by1 * SCALE);
    const float ew = rintf(bx2 * SCALE);
    const float eh = rintf(by2 * SCALE);
    const float bsh = fmaxf(eh - sh + 1.0f, 1.0f) * (1.0f / (float)PH);
    const float bsw = fmaxf(ew - sw + 1.0f, 1.0f) * (1.0f / (float)PW);

    const int hs = __builtin_amdgcn_readfirstlane(
        (int)fminf(fmaxf(floorf((float)i * bsh) + sh, 0.0f), (float)H_FEAT));
    const int he = __builtin_amdgcn_readfirstlane(
        (int)fminf(fmaxf(ceilf((float)(i + 1) * bsh) + sh, 0.0f), (float)H_FEAT));

    int ws[PW], we[PW];
    #pragma unroll
    for (int j = 0; j < PW; ++j) {
        ws[j] = __builtin_amdgcn_readfirstlane(
            (int)fminf(fmaxf(floorf((float)j * bsw) + sw, 0.0f), (float)W_FEAT));
        we[j] = __builtin_amdgcn_readfirstlane(
            (int)fminf(fmaxf(ceilf((float)(j + 1) * bsw) + sw, 0.0f), (float)W_FEAT));
    }

    // ---- pool: 2 channels/thread, uniform dynamic loops, NCHW direct ----
    const float* fc0 = f + (size_t)tid * P_FEAT;             // channel tid
    const float* fc1 = f + (size_t)(tid + TPB) * P_FEAT;     // channel tid+128

    float mx0[PW], mx1[PW];
    #pragma unroll
    for (int j = 0; j < PW; ++j) { mx0[j] = -1e30f; mx1[j] = -1e30f; }

    for (int y = hs; y < he; ++y) {
        const int yb = y * W_FEAT;
        #pragma unroll
        for (int j = 0; j < PW; ++j) {
            for (int x = ws[j]; x < we[j]; ++x) {   // uniform dynamic loop
                mx0[j] = fmaxf(mx0[j], fc0[yb + x]);
                mx1[j] = fmaxf(mx1[j], fc1[yb + x]);
            }
        }
    }

    const bool rowv = (he > hs);
    float* ob0 = out + (size_t)b * POOL_PER_BOX + (size_t)tid * CELLS + i * PW;
    float* ob1 = ob0 + (size_t)TPB * CELLS;
    #pragma unroll
    for (int j = 0; j < PW; ++j) {
        const bool val = rowv && (we[j] > ws[j]);
        ob0[j] = val ? mx0[j] : 0.0f;
        ob1[j] = val ? mx1[j] : 0.0f;
    }
}

// ---------------------------------------------------------------------------
extern "C" void kernel_launch(void* const* d_in, const int* in_sizes, int n_in,
                              void* d_out, int out_size, void* d_ws, size_t ws_size,
                              hipStream_t stream) {
    const float* features = (const float*)d_in[0];   // (1,256,40,40)
    const float* rois     = (const float*)d_in[1];   // (32,5)
    const int*   hh_p     = (const int*)d_in[2];
    const int*   hw_p     = (const int*)d_in[3];

    float* out = (float*)d_out;
    (void)d_ws; (void)ws_size; (void)in_sizes; (void)n_in; (void)out_size;

    // ONE launch, ZERO workspace use.
    hipLaunchKernelGGL(fused_v4, dim3(POOL_BLKS), dim3(TPB), 0, stream,
                       features, rois, hh_p, hw_p, out);
}

// Round 5
// 85.282 us; speedup vs baseline: 1.4704x; 1.4704x over previous
//
#include <hip/hip_runtime.h>
#include <math.h>

// Problem constants (from reference / setup_inputs)
#define N_ROIS   32
#define N_CAT    (N_ROIS * 9)      // 288 cat_rois rows
#define C_FEAT   256
#define H_FEAT   40
#define W_FEAT   40
#define P_FEAT   (H_FEAT * W_FEAT) // 1600 pixels
#define PH       7
#define PW       7
#define SCALE    0.0625f
#define MIN_SIZE 16.0f
#define CELLS    (PH * PW)                 // 49
#define POOL_PER_BOX (C_FEAT * CELLS)      // 12544
#define OUT_POOL_ELEMS ((size_t)N_CAT * POOL_PER_BOX)  // 3,612,672

// Fused-kernel geometry: block = (box, channel-quarter)
#define CH_G     64                         // channels per block
#define NCHG     4
#define NBLK     (N_CAT * NCHG)             // 1152 == 8 * 144 (XCD-bijective)
#define TPB      448                        // 64 ch x 7 pooled rows = 7 waves
#define WROWS    14                         // max window rows (bsh <= 2)
#define WCOLS    14                         // max window cols (bsw <= 2)
#define WELEM    (WROWS * WCOLS)            // 196
#define WSTRIDE  197                        // odd -> lane-stride 197%32=5,
                                            // gcd(5,32)=1: conflict-free reads
#define STAGE_ITERS ((CH_G * WELEM) / TPB)  // 28 exact

// ---------------------------------------------------------------------------
// v5: ONE launch (R3 evidence: fixed harness overhead = 55-57us regardless
// of kernel; a 2nd launch only adds). Kernel = R2's coalesced-LDS-staging
// structure minus its two measured diseases:
//  * R2 disease (43.6us): ~2500 VALU inst/thread of per-lane predicate
//    emulation of BLOCK-UNIFORM bounds, + one wave serially running a
//    650-inst IoU loop while 6 waves idle.
//    Fix: readfirstlane bounds -> SGPR dynamic loops (inner body =
//    ds_read + v_max only); lane-parallel IoU + shfl_xor butterfly argmax.
//  * v4 disease (70.3us, VALUBusy 13.6%): lane=channel over NCHW = 64
//    cache lines per wave load, serialized dependent scalar loads.
//    Fix: keep R2's x-fastest coalesced staging into LDS (consecutive
//    lanes -> consecutive addresses), fully unrolled (28 independent
//    loads, one vmcnt group).
// Occupancy: 50.4KB LDS -> 3 blocks/CU x 7 waves = 21 waves/CU.
// ---------------------------------------------------------------------------
__global__ __launch_bounds__(TPB) void
fused_v5(const float* __restrict__ f,
         const float* __restrict__ rois,
         const int* __restrict__ hh_p,
         const int* __restrict__ hw_p,
         float* __restrict__ out) {
    __shared__ __align__(16) float win[CH_G * WSTRIDE];   // 50,432 B

    const int bid  = blockIdx.x;
    // XCD-bijective swizzle (1152 = 8*144); box's 4 ch-quarters adjacent in s
    const int s    = (bid & 7) * (NBLK / 8) + (bid >> 3);
    const int b    = s >> 2;            // box 0..287
    const int cg   = s & 3;             // channel quarter
    const int tid  = threadIdx.x;
    const int lane = tid & 63;

    // ---- box geometry (block-uniform result; rois read via uniform loads) ----
    const int n  = b / 9;
    const int jj = b % 9;
    const float x1 = rois[n * 5 + 1], y1 = rois[n * 5 + 2];
    const float x2 = rois[n * 5 + 3], y2 = rois[n * 5 + 4];
    float bx1, by1, bx2, by2;

    if (jj == 0) {                      // parent roi row
        bx1 = x1; by1 = y1; bx2 = x2; by2 = y2;
    } else {
        const int j = jj - 1;
        const int m = (j < 4) ? j : j + 1;   // skip center of 3x3
        const int r  = m / 3;
        const int cc = m % 3;
        const float w = x2 - x1, h = y2 - y1;
        const float cx = x1 + w * ((float)cc - 0.5f);
        const float cy = y1 + h * ((float)r  - 0.5f);
        bx1 = cx - w * 0.25f;
        by1 = cy - h * 0.25f;
        bx2 = cx + w * 0.25f;
        by2 = cy + h * 0.25f;
        const float bw = bx2 - bx1 + 1.0f;
        const float bh = by2 - by1 + 1.0f;
        const float hh = (float)(*hh_p);
        const float hw = (float)(*hw_p);
        const bool invalid = (bx1 < 0.0f) || (by1 < 0.0f) ||
                             (bx2 >= hw) || (by2 >= hh) ||
                             (bw < MIN_SIZE) || (bh < MIN_SIZE);
        if (invalid) { bx1 = x1; by1 = y1; bx2 = x2; by2 = y2; }

        const float gw = bx2 - bx1 + 1.0f;
        const float gh = by2 - by1 + 1.0f;
        const float garea = gw * gh;
        const bool gdeg = (gw == 1.0f) && (gh == 1.0f);

        // ---- lane-parallel IoU: lane (a = lane&31) scores roi a ----
        const int a = lane & 31;
        const float ax1 = rois[a * 5 + 1], ay1 = rois[a * 5 + 2];
        const float ax2 = rois[a * 5 + 3], ay2 = rois[a * 5 + 4];
        const float aw = ax2 - ax1 + 1.0f, ah = ay2 - ay1 + 1.0f;
        const float iw = fmaxf(fminf(ax2, bx2) - fmaxf(ax1, bx1) + 1.0f, 0.0f);
        const float ih = fmaxf(fminf(ay2, by2) - fmaxf(ay1, by1) + 1.0f, 0.0f);
        const float inter = iw * ih;
        float ov = inter / (aw * ah + garea - inter);
        if (gdeg) ov = 0.0f;
        if (aw == 1.0f && ah == 1.0f) ov = -1.0f;
        int ai = a;
        // butterfly max+first-argmax over 64 lanes (two identical halves);
        // tie -> smaller index == jnp.argmax first-occurrence semantics
        #pragma unroll
        for (int off = 32; off >= 1; off >>= 1) {
            const float o2 = __shfl_xor(ov, off);
            const int   a2 = __shfl_xor(ai, off);
            if (o2 > ov || (o2 == ov && a2 < ai)) { ov = o2; ai = a2; }
        }

        bool label = (ov >= 0.3f);
        const float w_cell = bx2 - bx1;
        const float h_cell = by2 - by1;
        const float rw = label ? (rois[ai * 5 + 3] - rois[ai * 5 + 1]) : 0.0f;
        const float rh = label ? (rois[ai * 5 + 4] - rois[ai * 5 + 2]) : 0.0f;
        label = label &&
                !(fmaxf(rw, rh) >= fmaxf(w_cell, h_cell)) &&
                !(fminf(rw, rh) < fminf(w_cell, h_cell) / 3.0f);
        if (label) {
            bx1 = rois[ai * 5 + 1]; by1 = rois[ai * 5 + 2];
            bx2 = rois[ai * 5 + 3]; by2 = rois[ai * 5 + 4];
        }
    }

    // cat_rois output row (one writer per box)
    if (cg == 0 && tid == 0) {
        float* row = out + OUT_POOL_ELEMS + (size_t)b * 5;
        row[0] = (jj == 0) ? rois[n * 5] : 0.0f;
        row[1] = bx1; row[2] = by1; row[3] = bx2; row[4] = by2;
    }

    // ---- pooling geometry (block-uniform -> SGPRs) ----
    // jnp.round = round-half-to-even = rintf (default rounding mode)
    const float sw = rintf(bx1 * SCALE);
    const float sh = rintf(by1 * SCALE);
    const float ew = rintf(bx2 * SCALE);
    const float eh = rintf(by2 * SCALE);
    const float bsh = fmaxf(eh - sh + 1.0f, 1.0f) * (1.0f / (float)PH);
    const float bsw = fmaxf(ew - sw + 1.0f, 1.0f) * (1.0f / (float)PW);

    const int cl = tid & 63;          // local channel 0..63
    const int i  = tid >> 6;          // pooled row 0..6 (wave-uniform)

    const int hs = __builtin_amdgcn_readfirstlane(
        (int)fminf(fmaxf(floorf((float)i * bsh) + sh, 0.0f), (float)H_FEAT));
    const int he = __builtin_amdgcn_readfirstlane(
        (int)fminf(fmaxf(ceilf((float)(i + 1) * bsh) + sh, 0.0f), (float)H_FEAT));

    int ws[PW], we[PW];
    #pragma unroll
    for (int j = 0; j < PW; ++j) {
        ws[j] = __builtin_amdgcn_readfirstlane(
            (int)fminf(fmaxf(floorf((float)j * bsw) + sw, 0.0f), (float)W_FEAT));
        we[j] = __builtin_amdgcn_readfirstlane(
            (int)fminf(fmaxf(ceilf((float)(j + 1) * bsw) + sw, 0.0f), (float)W_FEAT));
    }
    const int xs = ws[0];                       // window col start (= clamp(sw))
    const int ys = __builtin_amdgcn_readfirstlane(
        (int)fminf(fmaxf(sh, 0.0f), (float)H_FEAT));  // window row start

    // bsw,bsh <= 2 guarantees span <= 14: we[6]-xs <= 14, he-ys <= 14
    // (holds for all boxes this data can produce; fallback kept for generality)
    const bool narrow = (bsw <= 2.0f) && (bsh <= 2.0f);   // block-uniform

    float mx[PW];
    #pragma unroll
    for (int j = 0; j < PW; ++j) mx[j] = -1e30f;

    if (narrow) {
        // ---- stage 64ch x 14x14 window NCHW -> LDS, fully unrolled ----
        // x-fastest flat index: consecutive lanes -> consecutive global
        // addresses (coalesced); 28 independent loads -> one vmcnt group.
        const int cbase = cg * CH_G;
        #pragma unroll
        for (int k = 0; k < STAGE_ITERS; ++k) {
            const int e  = tid + k * TPB;
            const int ch = e / WELEM;                 // magic-mul (const div)
            const int p  = e - ch * WELEM;
            const int yy = p / WCOLS;
            const int xx = p - yy * WCOLS;
            const int gy = (ys + yy < H_FEAT - 1) ? (ys + yy) : (H_FEAT - 1);
            const int gx = (xs + xx < W_FEAT - 1) ? (xs + xx) : (W_FEAT - 1);
            // clamped slots are never read by the uniform loops below
            win[ch * WSTRIDE + p] =
                f[(size_t)(cbase + ch) * P_FEAT + gy * W_FEAT + gx];
        }
        __syncthreads();

        // ---- uniform dynamic loops from LDS: ds_read + v_max only ----
        for (int y = hs; y < he; ++y) {
            const float* wr = win + cl * WSTRIDE + (y - ys) * WCOLS - xs;
            #pragma unroll
            for (int j = 0; j < PW; ++j)
                for (int x = ws[j]; x < we[j]; ++x)      // SGPR bounds
                    mx[j] = fmaxf(mx[j], wr[x]);
        }
    } else {
        // general fallback (not taken for this data): direct NCHW reads
        const int c = cg * CH_G + cl;
        for (int y = hs; y < he; ++y) {
            const float* fr = f + (size_t)c * P_FEAT + y * W_FEAT;
            #pragma unroll
            for (int j = 0; j < PW; ++j)
                for (int x = ws[j]; x < we[j]; ++x)
                    mx[j] = fmaxf(mx[j], fr[x]);
        }
    }

    // ---- stores: R2's exact pattern (measured WRITE_SIZE 14.1MB, fine) ----
    const bool rowv = (he > hs);
    const int c = cg * CH_G + cl;
    float* ob = out + (size_t)b * POOL_PER_BOX + (size_t)c * CELLS + i * PW;
    #pragma unroll
    for (int j = 0; j < PW; ++j)
        ob[j] = (rowv && (we[j] > ws[j])) ? mx[j] : 0.0f;
}

// ---------------------------------------------------------------------------
extern "C" void kernel_launch(void* const* d_in, const int* in_sizes, int n_in,
                              void* d_out, int out_size, void* d_ws, size_t ws_size,
                              hipStream_t stream) {
    const float* features = (const float*)d_in[0];   // (1,256,40,40)
    const float* rois     = (const float*)d_in[1];   // (32,5)
    const int*   hh_p     = (const int*)d_in[2];
    const int*   hw_p     = (const int*)d_in[3];

    float* out = (float*)d_out;
    (void)d_ws; (void)ws_size; (void)in_sizes; (void)n_in; (void)out_size;

    // ONE launch, ZERO workspace use (fixed overhead is per-iteration ~56us;
    // every extra launch only adds).
    hipLaunchKernelGGL(fused_v5, dim3(NBLK), dim3(TPB), 0, stream,
                       features, rois, hh_p, hw_p, out);
}

// Round 6
// 85.185 us; speedup vs baseline: 1.4721x; 1.0011x over previous
//
#include <hip/hip_runtime.h>
#include <math.h>

// Problem constants (from reference / setup_inputs)
#define N_ROIS   32
#define N_CAT    (N_ROIS * 9)      // 288 cat_rois rows
#define C_FEAT   256
#define H_FEAT   40
#define W_FEAT   40
#define P_FEAT   (H_FEAT * W_FEAT) // 1600 pixels
#define PH       7
#define PW       7
#define SCALE    0.0625f
#define MIN_SIZE 16.0f
#define CELLS    (PH * PW)                 // 49
#define POOL_PER_BOX (C_FEAT * CELLS)      // 12544
#define OUT_POOL_ELEMS ((size_t)N_CAT * POOL_PER_BOX)  // 3,612,672

// Fused-kernel geometry: block = (box, channel-quarter)
#define CH_G     64                         // channels per block
#define NCHG     4
#define NBLK     (N_CAT * NCHG)             // 1152 == 8 * 144 (XCD-bijective)
#define TPB      448                        // 64 ch x 7 pooled rows = 7 waves
#define WROWS    14                         // max window rows (bsh <= 2)
#define WCOLS    14                         // max window cols (bsw <= 2)
#define XSTRIDE  65                         // x-stride in floats (odd: no bank
                                            // conflicts on x-contig writes)
#define YSTRIDE  (WROWS * XSTRIDE)          // 910 floats per window row
// +220 slack: guarded reads may touch up to x=16 on the last row (lo<=14,
// lo+2<=16); those values are never USED (scalar-guarded), only loaded.
#define WIN_FLTS (WROWS * YSTRIDE + 220)    // 12,960 floats = 51,840 B

// ---------------------------------------------------------------------------
// v6: single launch (overhead model from R1/R3/R4: graded = ~53us fixed +
// kernel; every extra launch adds ~10us). Same proven geometry/IoU as v5
// (passed, absmax 0). Two v5 diseases fixed:
//  1. compute used DYNAMIC uniform loops over LDS -> one ds_read at a time,
//     issue+lgkmcnt(0)+fmax serialized (~120cy x ~30 per thread, thin
//     occupancy can't hide it). Since bsw<=2 => hi[j]-lo[j] <= 3, each cell
//     is now <=3 BATCHED ds_reads (static offsets 0/260/520) + <=3 fmax,
//     selected by wave-uniform SGPR guards (s_cmp, no per-lane predicates,
//     no dynamic trip counts).
//  2. staging spent ~280 VALU inst/thread on e/196, p/14 magic-div address
//     math. New divide-free map: ch=tid/7, m=tid%7; p=m+7k splits into
//     (y=q,x=m) and (y=q,x=m+7) -> 28 loads, ~2 VALU each, 28B-contiguous
//     global runs per 7-lane group (coalesced), conflict-free LDS writes.
// LDS layout win[y][x*65][ch]: writes x-contig (stride 65, odd -> free);
// compute reads lane-stride 1 (2-way aliasing = free) with static offsets.
// Occupancy: 51.8KB LDS -> 3 blocks/CU x 7 waves = 21 waves/CU.
// ---------------------------------------------------------------------------
__global__ __launch_bounds__(TPB) void
fused_v6(const float* __restrict__ f,
         const float* __restrict__ rois,
         const int* __restrict__ hh_p,
         const int* __restrict__ hw_p,
         float* __restrict__ out) {
    __shared__ __align__(16) float win[WIN_FLTS];   // 51,840 B

    const int bid  = blockIdx.x;
    // XCD-bijective swizzle (1152 = 8*144); box's 4 ch-quarters adjacent in s
    const int s    = (bid & 7) * (NBLK / 8) + (bid >> 3);
    const int b    = s >> 2;            // box 0..287
    const int cg   = s & 3;             // channel quarter
    const int tid  = threadIdx.x;
    const int lane = tid & 63;

    // ---- box geometry (block-uniform result; verbatim from v5: PASSED) ----
    const int n  = b / 9;
    const int jj = b % 9;
    const float x1 = rois[n * 5 + 1], y1 = rois[n * 5 + 2];
    const float x2 = rois[n * 5 + 3], y2 = rois[n * 5 + 4];
    float bx1, by1, bx2, by2;

    if (jj == 0) {                      // parent roi row
        bx1 = x1; by1 = y1; bx2 = x2; by2 = y2;
    } else {
        const int j = jj - 1;
        const int m = (j < 4) ? j : j + 1;   // skip center of 3x3
        const int r  = m / 3;
        const int cc = m % 3;
        const float w = x2 - x1, h = y2 - y1;
        const float cx = x1 + w * ((float)cc - 0.5f);
        const float cy = y1 + h * ((float)r  - 0.5f);
        bx1 = cx - w * 0.25f;
        by1 = cy - h * 0.25f;
        bx2 = cx + w * 0.25f;
        by2 = cy + h * 0.25f;
        const float bw = bx2 - bx1 + 1.0f;
        const float bh = by2 - by1 + 1.0f;
        const float hh = (float)(*hh_p);
        const float hw = (float)(*hw_p);
        const bool invalid = (bx1 < 0.0f) || (by1 < 0.0f) ||
                             (bx2 >= hw) || (by2 >= hh) ||
                             (bw < MIN_SIZE) || (bh < MIN_SIZE);
        if (invalid) { bx1 = x1; by1 = y1; bx2 = x2; by2 = y2; }

        const float gw = bx2 - bx1 + 1.0f;
        const float gh = by2 - by1 + 1.0f;
        const float garea = gw * gh;
        const bool gdeg = (gw == 1.0f) && (gh == 1.0f);

        // ---- lane-parallel IoU: lane (a = lane&31) scores roi a ----
        const int a = lane & 31;
        const float ax1 = rois[a * 5 + 1], ay1 = rois[a * 5 + 2];
        const float ax2 = rois[a * 5 + 3], ay2 = rois[a * 5 + 4];
        const float aw = ax2 - ax1 + 1.0f, ah = ay2 - ay1 + 1.0f;
        const float iw = fmaxf(fminf(ax2, bx2) - fmaxf(ax1, bx1) + 1.0f, 0.0f);
        const float ih = fmaxf(fminf(ay2, by2) - fmaxf(ay1, by1) + 1.0f, 0.0f);
        const float inter = iw * ih;
        float ov = inter / (aw * ah + garea - inter);
        if (gdeg) ov = 0.0f;
        if (aw == 1.0f && ah == 1.0f) ov = -1.0f;
        int ai = a;
        // butterfly max + FIRST-argmax (tie -> smaller index == jnp.argmax)
        #pragma unroll
        for (int off = 32; off >= 1; off >>= 1) {
            const float o2 = __shfl_xor(ov, off);
            const int   a2 = __shfl_xor(ai, off);
            if (o2 > ov || (o2 == ov && a2 < ai)) { ov = o2; ai = a2; }
        }

        bool label = (ov >= 0.3f);
        const float w_cell = bx2 - bx1;
        const float h_cell = by2 - by1;
        const float rw = label ? (rois[ai * 5 + 3] - rois[ai * 5 + 1]) : 0.0f;
        const float rh = label ? (rois[ai * 5 + 4] - rois[ai * 5 + 2]) : 0.0f;
        label = label &&
                !(fmaxf(rw, rh) >= fmaxf(w_cell, h_cell)) &&
                !(fminf(rw, rh) < fminf(w_cell, h_cell) / 3.0f);
        if (label) {
            bx1 = rois[ai * 5 + 1]; by1 = rois[ai * 5 + 2];
            bx2 = rois[ai * 5 + 3]; by2 = rois[ai * 5 + 4];
        }
    }

    // cat_rois output row (one writer per box)
    if (cg == 0 && tid == 0) {
        float* row = out + OUT_POOL_ELEMS + (size_t)b * 5;
        row[0] = (jj == 0) ? rois[n * 5] : 0.0f;
        row[1] = bx1; row[2] = by1; row[3] = bx2; row[4] = by2;
    }

    // ---- pooling geometry (block-uniform -> SGPRs) ----
    // jnp.round = round-half-to-even = rintf (default rounding mode)
    const float sw = rintf(bx1 * SCALE);
    const float sh = rintf(by1 * SCALE);
    const float ew = rintf(bx2 * SCALE);
    const float eh = rintf(by2 * SCALE);
    const float bsh = fmaxf(eh - sh + 1.0f, 1.0f) * (1.0f / (float)PH);
    const float bsw = fmaxf(ew - sw + 1.0f, 1.0f) * (1.0f / (float)PW);

    const int cl = tid & 63;          // local channel 0..63 (compute phase)
    const int i  = tid >> 6;          // pooled row 0..6 (wave-uniform)

    const int hs = __builtin_amdgcn_readfirstlane(
        (int)fminf(fmaxf(floorf((float)i * bsh) + sh, 0.0f), (float)H_FEAT));
    const int he = __builtin_amdgcn_readfirstlane(
        (int)fminf(fmaxf(ceilf((float)(i + 1) * bsh) + sh, 0.0f), (float)H_FEAT));

    int ws[PW], we[PW];
    #pragma unroll
    for (int j = 0; j < PW; ++j) {
        ws[j] = __builtin_amdgcn_readfirstlane(
            (int)fminf(fmaxf(floorf((float)j * bsw) + sw, 0.0f), (float)W_FEAT));
        we[j] = __builtin_amdgcn_readfirstlane(
            (int)fminf(fmaxf(ceilf((float)(j + 1) * bsw) + sw, 0.0f), (float)W_FEAT));
    }
    const int xs = ws[0];                       // window col start (= clamp(sw))
    const int ys = __builtin_amdgcn_readfirstlane(
        (int)fminf(fmaxf(sh, 0.0f), (float)H_FEAT));  // window row start

    // bsw,bsh <= 2 guarantees: he-ys<=14, we[6]-xs<=14, hi[j]-lo[j]<=3.
    // Always true for this data (max roi 200px -> bsw<=~1.94); fallback kept.
    const bool narrow = (bsw <= 2.0f) && (bsh <= 2.0f);   // block-uniform

    float mx[PW];
    #pragma unroll
    for (int j = 0; j < PW; ++j) mx[j] = -1e30f;

    if (narrow) {
        // ---- stage 64ch x 14x14 window NCHW -> LDS, divide-free ----
        // thread t: ch = t/7, m = t%7; covers x in {m, m+7}, y in 0..13.
        // 7-lane groups read 28B-contiguous global runs (coalesced);
        // LDS writes x-contig at stride 65 (odd -> conflict-free).
        {
            const int m  = tid % 7;
            const int ch = tid / 7;
            const int gx0 = (xs + m     < W_FEAT - 1) ? (xs + m)     : (W_FEAT - 1);
            const int gx1 = (xs + m + 7 < W_FEAT - 1) ? (xs + m + 7) : (W_FEAT - 1);
            const float* fch = f + (size_t)(cg * CH_G + ch) * P_FEAT;
            const int l0 = m * XSTRIDE + ch;
            #pragma unroll
            for (int q = 0; q < WROWS; ++q) {
                const int gy = (ys + q < H_FEAT - 1) ? (ys + q) : (H_FEAT - 1);
                const int gb = gy * W_FEAT;
                // clamped slots are never consumed (guards below)
                win[l0 + q * YSTRIDE]               = fch[gb + gx0];
                win[l0 + q * YSTRIDE + 7 * XSTRIDE] = fch[gb + gx1];
            }
        }
        __syncthreads();

        // ---- compute: per cell <=3 batched ds_reads + guarded fmax ----
        // lo[j],hi[j] wave-uniform SGPRs; nj = hi-lo in {<=0,1,2,3}.
        int lo[PW], nj[PW];
        #pragma unroll
        for (int j = 0; j < PW; ++j) {
            lo[j] = ws[j] - xs;              // 0..14
            nj[j] = we[j] - ws[j];           // <=3
        }
        for (int y = hs; y < he; ++y) {
            const float* wr = win + (y - ys) * YSTRIDE + cl;
            #pragma unroll
            for (int j = 0; j < PW; ++j) {
                // 3 independent reads, static offset immediates 0/260/520 B;
                // guarded-out reads land in the slack region (never used).
                const float* p0 = wr + lo[j] * XSTRIDE;
                const float d0 = p0[0];
                const float d1 = p0[XSTRIDE];
                const float d2 = p0[2 * XSTRIDE];
                if (nj[j] > 0) mx[j] = fmaxf(mx[j], d0);   // uniform guards
                if (nj[j] > 1) mx[j] = fmaxf(mx[j], d1);
                if (nj[j] > 2) mx[j] = fmaxf(mx[j], d2);
            }
        }
    } else {
        // general fallback (not taken for this data): direct NCHW reads
        const int c = cg * CH_G + cl;
        for (int y = hs; y < he; ++y) {
            const float* fr = f + (size_t)c * P_FEAT + y * W_FEAT;
            #pragma unroll
            for (int j = 0; j < PW; ++j)
                for (int x = ws[j]; x < we[j]; ++x)
                    mx[j] = fmaxf(mx[j], fr[x]);
        }
    }

    // ---- stores: scatter pattern (measured WRITE_SIZE 14.1MB in R1: fine) ----
    const bool rowv = (he > hs);
    const int c = cg * CH_G + cl;
    float* ob = out + (size_t)b * POOL_PER_BOX + (size_t)c * CELLS + i * PW;
    #pragma unroll
    for (int j = 0; j < PW; ++j)
        ob[j] = (rowv && (we[j] > ws[j])) ? mx[j] : 0.0f;
}

// ---------------------------------------------------------------------------
extern "C" void kernel_launch(void* const* d_in, const int* in_sizes, int n_in,
                              void* d_out, int out_size, void* d_ws, size_t ws_size,
                              hipStream_t stream) {
    const float* features = (const float*)d_in[0];   // (1,256,40,40)
    const float* rois     = (const float*)d_in[1];   // (32,5)
    const int*   hh_p     = (const int*)d_in[2];
    const int*   hw_p     = (const int*)d_in[3];

    float* out = (float*)d_out;
    (void)d_ws; (void)ws_size; (void)in_sizes; (void)n_in; (void)out_size;

    // ONE launch, ZERO workspace use.
    hipLaunchKernelGGL(fused_v6, dim3(NBLK), dim3(TPB), 0, stream,
                       features, rois, hh_p, hw_p, out);
}

// Round 7
// 78.141 us; speedup vs baseline: 1.6048x; 1.0901x over previous
//
#include <hip/hip_runtime.h>
#include <math.h>

// Problem constants (from reference / setup_inputs)
#define N_ROIS   32
#define N_CAT    (N_ROIS * 9)      // 288 cat_rois rows
#define C_FEAT   256
#define H_FEAT   40
#define W_FEAT   40
#define P_FEAT   (H_FEAT * W_FEAT) // 1600 pixels
#define PH       7
#define PW       7
#define SCALE    0.0625f
#define MIN_SIZE 16.0f
#define CELLS    (PH * PW)                 // 49
#define POOL_PER_BOX (C_FEAT * CELLS)      // 12544
#define OUT_POOL_ELEMS ((size_t)N_CAT * POOL_PER_BOX)  // 3,612,672

// Fused-kernel geometry: block = (box, channel-quarter)
#define CH_G     64                         // channels per block
#define NCHG     4
#define NBLK     (N_CAT * NCHG)             // 1152 == 8 * 144 (XCD-bijective)
#define TPB      448                        // 64 ch x 7 pooled rows = 7 waves
#define WROWS    14                         // max window rows (bsh <= 2)
#define NQ       5                          // aligned float4-quads per (ch,y):
                                            // [4*q0, 4*q0+19] covers any
                                            // 14-wide window (xs-4*q0 <= 3)
#define XF       (NQ * 4)                   // 20 floats per (ch,y)
#define CST      21                         // ch-stride (odd -> compute reads
                                            // lane-stride 21, gcd(21,32)=1: free)
#define YST      (CH_G * CST + 1)           // 1345 (== 1 mod 32: spreads writes)
#define WIN_FLTS (13 * YST + 63 * CST + XF) // 17,485+1,323+20 = 18,828 fl = 75.3KB
#define OBUF_FLTS (CH_G * CELLS)            // 3136 floats (overlays win after sync)
#define STAGE_N  (CH_G * WROWS * NQ)        // 4480 float4 = 10/thread exact

// ---------------------------------------------------------------------------
// v7: transaction-bound theory. All 7 prior measurements fit
// "dur ~= 2.5cy per 64B L1 line-request per CU":
//   v4 70.3us = 9.5K lines/blk x 7.9 blk/CU; v5=v6 29us = 5880 x 4.5.
// v6's VALU/latency fixes changed nothing because requests, not cycles,
// are the resource. v7 cuts lines/block 5880 -> ~2230:
//   reads:  28 scalar gathers -> 10 aligned float4 (2030 lines)
//   writes: 196B-stride scatter (3136 partial lines) -> LDS obuf +
//           dense float4 drain of the contiguous out[b][cg*3136..] slice
//           (196 full lines, 16x cut)
// Geometry/IoU/guards verbatim from v6 (passed, absmax 0).
// LDS win[y][ch*21 + xoff]: compute reads stride-21 (free); stage writes
// <=4-way (cheap); obuf (ch*49+cell, stride 49 odd: free) overlays win
// after sync#2. 75.3KB -> 2 blocks/CU x 7 waves = 14 waves/CU.
// ---------------------------------------------------------------------------
__global__ __launch_bounds__(TPB) void
fused_v7(const float* __restrict__ f,
         const float* __restrict__ rois,
         const int* __restrict__ hh_p,
         const int* __restrict__ hw_p,
         float* __restrict__ out) {
    __shared__ __align__(16) float win[WIN_FLTS];   // 75,312 B

    const int bid  = blockIdx.x;
    // XCD-bijective swizzle (1152 = 8*144); box's 4 ch-quarters adjacent in s
    const int s    = (bid & 7) * (NBLK / 8) + (bid >> 3);
    const int b    = s >> 2;            // box 0..287
    const int cg   = s & 3;             // channel quarter
    const int tid  = threadIdx.x;
    const int lane = tid & 63;

    // ---- box geometry (block-uniform result; verbatim from v5/v6: PASSED) ----
    const int n  = b / 9;
    const int jj = b % 9;
    const float x1 = rois[n * 5 + 1], y1 = rois[n * 5 + 2];
    const float x2 = rois[n * 5 + 3], y2 = rois[n * 5 + 4];
    float bx1, by1, bx2, by2;

    if (jj == 0) {                      // parent roi row
        bx1 = x1; by1 = y1; bx2 = x2; by2 = y2;
    } else {
        const int j = jj - 1;
        const int m = (j < 4) ? j : j + 1;   // skip center of 3x3
        const int r  = m / 3;
        const int cc = m % 3;
        const float w = x2 - x1, h = y2 - y1;
        const float cx = x1 + w * ((float)cc - 0.5f);
        const float cy = y1 + h * ((float)r  - 0.5f);
        bx1 = cx - w * 0.25f;
        by1 = cy - h * 0.25f;
        bx2 = cx + w * 0.25f;
        by2 = cy + h * 0.25f;
        const float bw = bx2 - bx1 + 1.0f;
        const float bh = by2 - by1 + 1.0f;
        const float hh = (float)(*hh_p);
        const float hw = (float)(*hw_p);
        const bool invalid = (bx1 < 0.0f) || (by1 < 0.0f) ||
                             (bx2 >= hw) || (by2 >= hh) ||
                             (bw < MIN_SIZE) || (bh < MIN_SIZE);
        if (invalid) { bx1 = x1; by1 = y1; bx2 = x2; by2 = y2; }

        const float gw = bx2 - bx1 + 1.0f;
        const float gh = by2 - by1 + 1.0f;
        const float garea = gw * gh;
        const bool gdeg = (gw == 1.0f) && (gh == 1.0f);

        // ---- lane-parallel IoU: lane (a = lane&31) scores roi a ----
        const int a = lane & 31;
        const float ax1 = rois[a * 5 + 1], ay1 = rois[a * 5 + 2];
        const float ax2 = rois[a * 5 + 3], ay2 = rois[a * 5 + 4];
        const float aw = ax2 - ax1 + 1.0f, ah = ay2 - ay1 + 1.0f;
        const float iw = fmaxf(fminf(ax2, bx2) - fmaxf(ax1, bx1) + 1.0f, 0.0f);
        const float ih = fmaxf(fminf(ay2, by2) - fmaxf(ay1, by1) + 1.0f, 0.0f);
        const float inter = iw * ih;
        float ov = inter / (aw * ah + garea - inter);
        if (gdeg) ov = 0.0f;
        if (aw == 1.0f && ah == 1.0f) ov = -1.0f;
        int ai = a;
        // butterfly max + FIRST-argmax (tie -> smaller index == jnp.argmax)
        #pragma unroll
        for (int off = 32; off >= 1; off >>= 1) {
            const float o2 = __shfl_xor(ov, off);
            const int   a2 = __shfl_xor(ai, off);
            if (o2 > ov || (o2 == ov && a2 < ai)) { ov = o2; ai = a2; }
        }

        bool label = (ov >= 0.3f);
        const float w_cell = bx2 - bx1;
        const float h_cell = by2 - by1;
        const float rw = label ? (rois[ai * 5 + 3] - rois[ai * 5 + 1]) : 0.0f;
        const float rh = label ? (rois[ai * 5 + 4] - rois[ai * 5 + 2]) : 0.0f;
        label = label &&
                !(fmaxf(rw, rh) >= fmaxf(w_cell, h_cell)) &&
                !(fminf(rw, rh) < fminf(w_cell, h_cell) / 3.0f);
        if (label) {
            bx1 = rois[ai * 5 + 1]; by1 = rois[ai * 5 + 2];
            bx2 = rois[ai * 5 + 3]; by2 = rois[ai * 5 + 4];
        }
    }

    // cat_rois output row (one writer per box)
    if (cg == 0 && tid == 0) {
        float* row = out + OUT_POOL_ELEMS + (size_t)b * 5;
        row[0] = (jj == 0) ? rois[n * 5] : 0.0f;
        row[1] = bx1; row[2] = by1; row[3] = bx2; row[4] = by2;
    }

    // ---- pooling geometry (block-uniform -> SGPRs) ----
    // jnp.round = round-half-to-even = rintf (default rounding mode)
    const float sw = rintf(bx1 * SCALE);
    const float sh = rintf(by1 * SCALE);
    const float ew = rintf(bx2 * SCALE);
    const float eh = rintf(by2 * SCALE);
    const float bsh = fmaxf(eh - sh + 1.0f, 1.0f) * (1.0f / (float)PH);
    const float bsw = fmaxf(ew - sw + 1.0f, 1.0f) * (1.0f / (float)PW);

    const int cl = tid & 63;          // local channel 0..63 (compute phase)
    const int i  = tid >> 6;          // pooled row 0..6 (wave-uniform)

    const int hs = __builtin_amdgcn_readfirstlane(
        (int)fminf(fmaxf(floorf((float)i * bsh) + sh, 0.0f), (float)H_FEAT));
    const int he = __builtin_amdgcn_readfirstlane(
        (int)fminf(fmaxf(ceilf((float)(i + 1) * bsh) + sh, 0.0f), (float)H_FEAT));

    int ws[PW], we[PW];
    #pragma unroll
    for (int j = 0; j < PW; ++j) {
        ws[j] = __builtin_amdgcn_readfirstlane(
            (int)fminf(fmaxf(floorf((float)j * bsw) + sw, 0.0f), (float)W_FEAT));
        we[j] = __builtin_amdgcn_readfirstlane(
            (int)fminf(fmaxf(ceilf((float)(j + 1) * bsw) + sw, 0.0f), (float)W_FEAT));
    }
    const int xs = ws[0];                       // window col start (= clamp(sw))
    const int ys = __builtin_amdgcn_readfirstlane(
        (int)fminf(fmaxf(sh, 0.0f), (float)H_FEAT));  // window row start
    const int q0 = xs >> 2;                     // aligned quad base

    // bsw,bsh <= 2 guarantees: he-ys<=14, we[6]-xs<=14, we[j]-ws[j]<=3,
    // and ws[6]-4*q0+2 <= 17 < XF. Always true for this data; fallback kept.
    const bool narrow = (bsw <= 2.0f) && (bsh <= 2.0f);   // block-uniform

    const bool rowv = (he > hs);

    if (narrow) {
        // ---- stage: 64ch x 14y x 5 aligned float4, NCHW -> LDS ----
        // 4480 float4 / 448 threads = 10 each. Per wave-instr: 64 lanes x
        // 16B over ~13 (ch,y)-rows of 80B -> ~29 lines (vs ~96 scalar-era).
        const float* fbase = f + (size_t)(cg * CH_G) * P_FEAT;
        #pragma unroll
        for (int t = 0; t < STAGE_N / TPB; ++t) {
            const int e  = tid + t * TPB;
            const int k  = e % NQ;                   // quad 0..4 (const-div)
            const int rc = e / NQ;                   // (ch,y) 0..895
            const int yy = rc % WROWS;
            const int ch = rc / WROWS;
            const int gy = (ys + yy < H_FEAT - 1) ? (ys + yy) : (H_FEAT - 1);
            const int gq = (q0 + k < (W_FEAT / 4) - 1) ? (q0 + k) : (W_FEAT / 4) - 1;
            // clamped slots hold duplicates; used x<=39 always maps to an
            // unclamped slot (x-4*q0 indexes quad (x>>2)-q0 with q0+k<=9)
            const float4 v = *(const float4*)(fbase + (size_t)ch * P_FEAT
                                              + gy * W_FEAT + gq * 4);
            float* wp = win + yy * YST + ch * CST + k * 4;
            wp[0] = v.x; wp[1] = v.y; wp[2] = v.z; wp[3] = v.w;
        }
        __syncthreads();

        // ---- compute: per cell <=3 ds_reads + wave-uniform guarded fmax ----
        float mx[PW];
        #pragma unroll
        for (int j = 0; j < PW; ++j) mx[j] = -1e30f;

        int off[PW], nj[PW];
        #pragma unroll
        for (int j = 0; j < PW; ++j) {
            off[j] = ws[j] - 4 * q0;         // 0..17 (SGPR)
            nj[j]  = we[j] - ws[j];          // 0..3  (SGPR)
        }
        for (int y = hs; y < he; ++y) {
            const float* wr = win + (y - ys) * YST + cl * CST;
            #pragma unroll
            for (int j = 0; j < PW; ++j) {
                const float* p0 = wr + off[j];
                const float d0 = p0[0];
                const float d1 = p0[1];
                const float d2 = p0[2];
                if (nj[j] > 0) mx[j] = fmaxf(mx[j], d0);   // uniform guards
                if (nj[j] > 1) mx[j] = fmaxf(mx[j], d1);
                if (nj[j] > 2) mx[j] = fmaxf(mx[j], d2);
            }
        }
        __syncthreads();    // all win reads done -> safe to overlay obuf

        // ---- obuf (overlays win): scalar writes, stride 49 (odd: free) ----
        float* orow = win + cl * CELLS + i * PW;
        #pragma unroll
        for (int j = 0; j < PW; ++j)
            orow[j] = (rowv && (nj[j] > 0)) ? mx[j] : 0.0f;
        __syncthreads();

        // ---- dense drain: 784 float4 -> contiguous out slice (196 lines) ----
        const float4* src = (const float4*)win;
        float4* dst = (float4*)(out + (size_t)b * POOL_PER_BOX
                                    + (size_t)cg * OBUF_FLTS);
        dst[tid] = src[tid];
        const int e2 = tid + TPB;
        if (e2 < OBUF_FLTS / 4) dst[e2] = src[e2];
    } else {
        // general fallback (not taken for this data): direct NCHW reads,
        // direct scatter stores (correct, slow)
        const int c = cg * CH_G + cl;
        float mx[PW];
        #pragma unroll
        for (int j = 0; j < PW; ++j) mx[j] = -1e30f;
        for (int y = hs; y < he; ++y) {
            const float* fr = f + (size_t)c * P_FEAT + y * W_FEAT;
            #pragma unroll
            for (int j = 0; j < PW; ++j)
                for (int x = ws[j]; x < we[j]; ++x)
                    mx[j] = fmaxf(mx[j], fr[x]);
        }
        float* ob = out + (size_t)b * POOL_PER_BOX + (size_t)c * CELLS + i * PW;
        #pragma unroll
        for (int j = 0; j < PW; ++j)
            ob[j] = (rowv && (we[j] > ws[j])) ? mx[j] : 0.0f;
    }
}

// ---------------------------------------------------------------------------
extern "C" void kernel_launch(void* const* d_in, const int* in_sizes, int n_in,
                              void* d_out, int out_size, void* d_ws, size_t ws_size,
                              hipStream_t stream) {
    const float* features = (const float*)d_in[0];   // (1,256,40,40)
    const float* rois     = (const float*)d_in[1];   // (32,5)
    const int*   hh_p     = (const int*)d_in[2];
    const int*   hw_p     = (const int*)d_in[3];

    float* out = (float*)d_out;
    (void)d_ws; (void)ws_size; (void)in_sizes; (void)n_in; (void)out_size;

    // ONE launch, ZERO workspace use (graded = ~56us fixed + kernel).
    hipLaunchKernelGGL(fused_v7, dim3(NBLK), dim3(TPB), 0, stream,
                       features, rois, hh_p, hw_p, out);
}